// Round 1
// baseline (317.507 us; speedup 1.0000x reference)
//
#include <hip/hip_runtime.h>
#include <stdint.h>

// AttentionLayer_27599459844127 — round 0: correctness-first bf16-MFMA pipeline.
// B=4,S=1024,D=1024,H=16,DH=64. All heavy GEMMs via mfma_f32_16x16x32_bf16.

typedef __attribute__((ext_vector_type(8))) short short8;
typedef __attribute__((ext_vector_type(4))) float f32x4;
typedef __attribute__((ext_vector_type(4))) unsigned short ushort4v;

#define DEVI __device__ __forceinline__

constexpr float NEG_MIN = -3.4028234663852886e38f;
constexpr float LOG2E   = 1.4426950408889634f;

DEVI unsigned short f2b(float f) {
    union { float f; unsigned u; } x; x.f = f;
    unsigned u = x.u;
    unsigned r = (u + 0x7fffu + ((u >> 16) & 1u)) >> 16;  // RNE
    return (unsigned short)r;
}
DEVI float b2f(unsigned short b) {
    union { unsigned u; float f; } x; x.u = ((unsigned)b) << 16;
    return x.f;
}

// ---------------- cast f32 -> bf16 (vectorized) ----------------
__global__ void __launch_bounds__(256) cast_f32_bf16(const float* __restrict__ src,
                                                     unsigned short* __restrict__ dst, int n4) {
    int i = blockIdx.x * 256 + threadIdx.x;
    if (i >= n4) return;
    float4 v = reinterpret_cast<const float4*>(src)[i];
    ushort4v o;
    o.x = f2b(v.x); o.y = f2b(v.y); o.z = f2b(v.z); o.w = f2b(v.w);
    reinterpret_cast<ushort4v*>(dst)[i] = o;
}

// ---------------- transpose + cast: src f32 [R][C] -> dst bf16 [C][R] ----------------
__global__ void __launch_bounds__(256) transpose_cast(const float* __restrict__ src,
                                                      unsigned short* __restrict__ dst,
                                                      int R, int C) {
    __shared__ float t[64][65];
    int ctiles = C >> 6;
    int bc = blockIdx.x % ctiles, br = blockIdx.x / ctiles;
    int tid = threadIdx.x;
    int r0 = tid >> 4, c4 = (tid & 15) << 2;
    for (int i = 0; i < 4; ++i) {
        int row = r0 + i * 16;
        float4 v = *reinterpret_cast<const float4*>(&src[(size_t)(br * 64 + row) * C + bc * 64 + c4]);
        t[row][c4] = v.x; t[row][c4 + 1] = v.y; t[row][c4 + 2] = v.z; t[row][c4 + 3] = v.w;
    }
    __syncthreads();
    int cr0 = tid >> 4, r4 = (tid & 15) << 2;
    for (int i = 0; i < 4; ++i) {
        int crow = cr0 + i * 16;
        ushort4v o;
        o.x = f2b(t[r4][crow]); o.y = f2b(t[r4 + 1][crow]);
        o.z = f2b(t[r4 + 2][crow]); o.w = f2b(t[r4 + 3][crow]);
        *reinterpret_cast<ushort4v*>(&dst[(size_t)(bc * 64 + crow) * R + br * 64 + r4]) = o;
    }
}

// ---------------- GEMM: C[M,N] = A[M,K] @ Bt[N,K]^T, bf16 in, bf16/f32 out ----------------
// 128x128 tile, BK=32, 256 threads = 4 waves (2x2), each wave 64x64 via 4x4 mfma 16x16x32.
template <int OUT_F32>
__global__ void __launch_bounds__(256) gemm_bt(const unsigned short* __restrict__ A,
                                               const unsigned short* __restrict__ Bt,
                                               void* __restrict__ Cv,
                                               int M, int N, int Kd, int nbn) {
    __shared__ unsigned short As[128 * 40];  // rows padded to 40 shorts (80B) -> conflict-free b128
    __shared__ unsigned short Bs[128 * 40];
    int bm = blockIdx.x / nbn, bn = blockIdx.x % nbn;
    int tid = threadIdx.x, l = tid & 63, w = tid >> 6;
    int wm = w >> 1, wn = w & 1;
    int l15 = l & 15, koff = (l >> 4) << 3;
    f32x4 acc[4][4] = {};
    const int arow = tid >> 2, acol = (tid & 3) << 3;
    const unsigned short* Ab = A + (size_t)(bm * 128) * Kd;
    const unsigned short* Bb = Bt + (size_t)(bn * 128) * Kd;
    for (int kt = 0; kt < Kd; kt += 32) {
        short8 va0 = *reinterpret_cast<const short8*>(&Ab[(size_t)arow * Kd + kt + acol]);
        short8 va1 = *reinterpret_cast<const short8*>(&Ab[(size_t)(arow + 64) * Kd + kt + acol]);
        short8 vb0 = *reinterpret_cast<const short8*>(&Bb[(size_t)arow * Kd + kt + acol]);
        short8 vb1 = *reinterpret_cast<const short8*>(&Bb[(size_t)(arow + 64) * Kd + kt + acol]);
        __syncthreads();  // previous iter's frag reads done before overwrite
        *reinterpret_cast<short8*>(&As[arow * 40 + acol]) = va0;
        *reinterpret_cast<short8*>(&As[(arow + 64) * 40 + acol]) = va1;
        *reinterpret_cast<short8*>(&Bs[arow * 40 + acol]) = vb0;
        *reinterpret_cast<short8*>(&Bs[(arow + 64) * 40 + acol]) = vb1;
        __syncthreads();
        short8 af[4], bf[4];
        for (int m = 0; m < 4; ++m)
            af[m] = *reinterpret_cast<const short8*>(&As[(wm * 64 + m * 16 + l15) * 40 + koff]);
        for (int n = 0; n < 4; ++n)
            bf[n] = *reinterpret_cast<const short8*>(&Bs[(wn * 64 + n * 16 + l15) * 40 + koff]);
        for (int m = 0; m < 4; ++m)
            for (int n = 0; n < 4; ++n)
                acc[m][n] = __builtin_amdgcn_mfma_f32_16x16x32_bf16(af[m], bf[n], acc[m][n], 0, 0, 0);
    }
    for (int m = 0; m < 4; ++m)
        for (int n = 0; n < 4; ++n)
            for (int r = 0; r < 4; ++r) {
                int row = bm * 128 + wm * 64 + m * 16 + ((l >> 4) << 2) + r;
                int col = bn * 128 + wn * 64 + n * 16 + l15;
                float v = acc[m][n][r];
                if (OUT_F32) reinterpret_cast<float*>(Cv)[(size_t)row * N + col] = v;
                else reinterpret_cast<unsigned short*>(Cv)[(size_t)row * N + col] = f2b(v);
            }
}

// ---------------- k_red[b,s,h] = sum_a K[b,s,h,a] ----------------
__global__ void __launch_bounds__(256) kred_kernel(const unsigned short* __restrict__ K,
                                                   float* __restrict__ kred) {
    int idx = blockIdx.x * 256 + threadIdx.x;  // B*S*H = 65536
    const unsigned short* p = K + (size_t)idx * 64;
    float s = 0.f;
    for (int c = 0; c < 8; ++c) {
        short8 v = *reinterpret_cast<const short8*>(&p[c * 8]);
        for (int j = 0; j < 8; ++j) s += b2f((unsigned short)v[j]);
    }
    kred[idx] = s;
}

// ---------------- V [B,S,H,DH] -> Vt [B,H,DH,S] (bf16) ----------------
__global__ void __launch_bounds__(256) transpose_v(const unsigned short* __restrict__ V,
                                                   unsigned short* __restrict__ Vt) {
    __shared__ unsigned short t[64][66];
    int bid = blockIdx.x;
    int st = bid & 15, h = (bid >> 4) & 15, b = bid >> 8;
    int tid = threadIdx.x;
    int s = tid >> 2, c16 = (tid & 3) << 4;
    const unsigned short* src = V + ((size_t)((b * 1024 + st * 64 + s) * 16 + h)) * 64 + c16;
    short8 v0 = *reinterpret_cast<const short8*>(src);
    short8 v1 = *reinterpret_cast<const short8*>(src + 8);
    for (int j = 0; j < 8; ++j) {
        t[s][c16 + j] = (unsigned short)v0[j];
        t[s][c16 + 8 + j] = (unsigned short)v1[j];
    }
    __syncthreads();
    int a = tid >> 2, s16 = (tid & 3) << 4;
    short8 o0, o1;
    for (int j = 0; j < 8; ++j) {
        o0[j] = (short)t[s16 + j][a];
        o1[j] = (short)t[s16 + 8 + j][a];
    }
    unsigned short* dst = Vt + ((size_t)((b * 16 + h) * 64 + a)) * 1024 + st * 64 + s16;
    *reinterpret_cast<short8*>(dst) = o0;
    *reinterpret_cast<short8*>(dst + 8) = o1;
}

// ---------------- sparse bias scatter: bqk[b,q,k] += embs[e]·scal ----------------
__global__ void __launch_bounds__(256) scatter_bias(const int* __restrict__ ab,
                                                    const float* __restrict__ embs,
                                                    const float* __restrict__ scal,
                                                    float* __restrict__ bqk, int n) {
    int i = blockIdx.x * 256 + threadIdx.x;
    if (i >= n) return;
    int b = ab[i * 4], q = ab[i * 4 + 1], k = ab[i * 4 + 2], e = ab[i * 4 + 3];
    float v = 0.f;
    for (int a = 0; a < 64; ++a) v += embs[e * 64 + a] * scal[a];
    atomicAdd(&bqk[((size_t)b * 1024 + q) * 1024 + k], v);
}

// ---------------- fused attention (flash-style, online softmax) ----------------
// grid = B * (S/16) * 4 hgroups; block = 256 thr = 4 waves; wave w -> head hg*4+w, 16 q-rows.
__global__ void __launch_bounds__(256) attn_kernel(const unsigned short* __restrict__ Q,
                                                   const unsigned short* __restrict__ K,
                                                   const unsigned short* __restrict__ Vt,
                                                   const float* __restrict__ bqk,
                                                   const float* __restrict__ kred,
                                                   const float* __restrict__ masks,
                                                   unsigned short* __restrict__ ctx) {
    __shared__ float bqk_s[16][65];
    __shared__ float mask_s[16][65];
    __shared__ float kred_s[64][17];
    __shared__ unsigned short p_s[4][16][72];  // per-wave P tile, 16B-aligned padded rows

    int bid = blockIdx.x;
    int hg = bid & 3, qt = (bid >> 2) & 63, b = bid >> 8;
    int tid = threadIdx.x, w = tid >> 6, l = tid & 63;
    int h = hg * 4 + w;
    int qbase = qt * 16;
    int l15 = l & 15, l16 = l >> 4;
    int koff = l16 << 3;

    short8 qf[2];
    {
        const unsigned short* qp = Q + ((size_t)((b * 1024 + qbase + l15) * 16 + h)) * 64 + koff;
        qf[0] = *reinterpret_cast<const short8*>(qp);
        qf[1] = *reinterpret_cast<const short8*>(qp + 32);
    }
    float m_r[4], l_r[4];
    f32x4 O[4] = {};
    for (int r = 0; r < 4; ++r) { m_r[r] = -INFINITY; l_r[r] = 0.f; }

    int srow = tid >> 4, sc4 = (tid & 15) << 2;  // 16x64 tile staging
    int skk = tid >> 2, sh4 = (tid & 3) << 2;    // 64x16 kred staging

    for (int kt = 0; kt < 16; ++kt) {
        int kbase = kt * 64;
        {
            float4 v = *reinterpret_cast<const float4*>(
                &bqk[((size_t)(b * 1024 + qbase + srow)) * 1024 + kbase + sc4]);
            bqk_s[srow][sc4] = v.x; bqk_s[srow][sc4 + 1] = v.y;
            bqk_s[srow][sc4 + 2] = v.z; bqk_s[srow][sc4 + 3] = v.w;
            float4 mv = *reinterpret_cast<const float4*>(
                &masks[((size_t)(b * 1024 + qbase + srow)) * 1024 + kbase + sc4]);
            mask_s[srow][sc4] = mv.x; mask_s[srow][sc4 + 1] = mv.y;
            mask_s[srow][sc4 + 2] = mv.z; mask_s[srow][sc4 + 3] = mv.w;
            float4 kv = *reinterpret_cast<const float4*>(
                &kred[((size_t)(b * 1024 + kbase + skk)) * 16 + sh4]);
            kred_s[skk][sh4] = kv.x; kred_s[skk][sh4 + 1] = kv.y;
            kred_s[skk][sh4 + 2] = kv.z; kred_s[skk][sh4 + 3] = kv.w;
        }
        __syncthreads();

        // QK^T (A=Q rows, B=K rows -> S[q][kcol])
        f32x4 sacc[4] = {};
        for (int n = 0; n < 4; ++n) {
            const unsigned short* kp =
                K + ((size_t)((b * 1024 + kbase + n * 16 + l15) * 16 + h)) * 64 + koff;
            short8 kf0 = *reinterpret_cast<const short8*>(kp);
            short8 kf1 = *reinterpret_cast<const short8*>(kp + 32);
            sacc[n] = __builtin_amdgcn_mfma_f32_16x16x32_bf16(qf[0], kf0, sacc[n], 0, 0, 0);
            sacc[n] = __builtin_amdgcn_mfma_f32_16x16x32_bf16(qf[1], kf1, sacc[n], 0, 0, 0);
        }

        // bias + scale + mask -> logits
        float logit[4][4], tmax[4];
        for (int r = 0; r < 4; ++r) tmax[r] = -INFINITY;
        for (int n = 0; n < 4; ++n) {
            int col = n * 16 + l15;
            float krv = kred_s[col][h];
            for (int r = 0; r < 4; ++r) {
                int row = l16 * 4 + r;
                float sv = (sacc[n][r] + bqk_s[row][col] * krv) * 0.125f;
                float mv = mask_s[row][col];
                float lg = sv * mv + (1.f - ceilf(mv)) * NEG_MIN;
                logit[n][r] = lg;
                tmax[r] = fmaxf(tmax[r], lg);
            }
        }
        for (int d = 1; d < 16; d <<= 1)
            for (int r = 0; r < 4; ++r) tmax[r] = fmaxf(tmax[r], __shfl_xor(tmax[r], d));
        float alpha[4], psum[4];
        for (int r = 0; r < 4; ++r) {
            float nm = fmaxf(m_r[r], tmax[r]);
            alpha[r] = exp2f((m_r[r] - nm) * LOG2E);
            m_r[r] = nm;
            psum[r] = 0.f;
        }
        for (int n = 0; n < 4; ++n) {
            int col = n * 16 + l15;
            for (int r = 0; r < 4; ++r) {
                int row = l16 * 4 + r;
                float p = exp2f((logit[n][r] - m_r[r]) * LOG2E);
                psum[r] += p;
                p_s[w][row][col] = f2b(p * mask_s[row][col]);  // numerator masked, denom not
            }
        }
        for (int d = 1; d < 16; d <<= 1)
            for (int r = 0; r < 4; ++r) psum[r] += __shfl_xor(psum[r], d);
        for (int r = 0; r < 4; ++r) l_r[r] = l_r[r] * alpha[r] + psum[r];
        for (int af = 0; af < 4; ++af)
            for (int r = 0; r < 4; ++r) O[af][r] *= alpha[r];
        __syncthreads();  // p_s visible; all waves done reading staged tiles

        // PV: A = P tile (LDS), B = Vt rows (global)
        for (int ks = 0; ks < 2; ++ks) {
            short8 pa = *reinterpret_cast<const short8*>(&p_s[w][l15][ks * 32 + koff]);
            for (int af = 0; af < 4; ++af) {
                const unsigned short* vp =
                    Vt + ((size_t)((b * 16 + h) * 64 + af * 16 + l15)) * 1024 + kbase + ks * 32 + koff;
                short8 vb = *reinterpret_cast<const short8*>(vp);
                O[af] = __builtin_amdgcn_mfma_f32_16x16x32_bf16(pa, vb, O[af], 0, 0, 0);
            }
        }
    }

    for (int af = 0; af < 4; ++af)
        for (int r = 0; r < 4; ++r) {
            int row = l16 * 4 + r;
            float v = O[af][r] / l_r[r];
            ctx[((size_t)((b * 1024 + qbase + row) * 16 + h)) * 64 + af * 16 + l15] = f2b(v);
        }
}

// ---------------- host launch ----------------
extern "C" void kernel_launch(void* const* d_in, const int* in_sizes, int n_in,
                              void* d_out, int out_size, void* d_ws, size_t ws_size,
                              hipStream_t stream) {
    const float* states     = (const float*)d_in[0];
    const float* key_states = (const float*)d_in[1];
    const float* masks      = (const float*)d_in[2];
    const int*   ab         = (const int*)d_in[3];
    const float* Wq         = (const float*)d_in[4];
    const float* Wk         = (const float*)d_in[5];
    const float* Wv         = (const float*)d_in[6];
    const float* Wo         = (const float*)d_in[7];
    const float* embs       = (const float*)d_in[8];
    const float* scal       = (const float*)d_in[9];

    char* ws = (char*)d_ws;
    const size_t MB = 1024 * 1024;
    // [0,16)MB: Sb+Kb early, then bqk (f32, 16MB) after the GEMMs are done with them.
    unsigned short* Sb  = (unsigned short*)(ws);
    unsigned short* Kb  = (unsigned short*)(ws + 8 * MB);
    float*          bqk = (float*)(ws);
    unsigned short* Wqt = (unsigned short*)(ws + 16 * MB);  // 3 x 2MB (Wq^T,Wk^T,Wv^T)
    unsigned short* Wot = (unsigned short*)(ws + 22 * MB);
    unsigned short* Qb  = (unsigned short*)(ws + 24 * MB);
    unsigned short* Kbf = (unsigned short*)(ws + 32 * MB);
    unsigned short* Vb  = (unsigned short*)(ws + 40 * MB);  // dead after transpose_v
    unsigned short* ctx = (unsigned short*)(ws + 40 * MB);  // reuses Vb region
    unsigned short* Vt  = (unsigned short*)(ws + 48 * MB);
    float*          krd = (float*)(ws + 56 * MB);           // 256KB
    (void)in_sizes; (void)n_in; (void)out_size; (void)ws_size;

    cast_f32_bf16<<<4096, 256, 0, stream>>>(states, Sb, 1024 * 1024);
    cast_f32_bf16<<<4096, 256, 0, stream>>>(key_states, Kb, 1024 * 1024);
    transpose_cast<<<256, 256, 0, stream>>>(Wq, Wqt, 1024, 1024);
    transpose_cast<<<256, 256, 0, stream>>>(Wk, Wqt + 1024 * 1024, 1024, 1024);
    transpose_cast<<<256, 256, 0, stream>>>(Wv, Wqt + 2 * 1024 * 1024, 1024, 1024);
    transpose_cast<<<256, 256, 0, stream>>>(Wo, Wot, 1024, 1024);

    gemm_bt<0><<<256, 256, 0, stream>>>(Sb, Wqt, Qb, 4096, 1024, 1024, 8);
    gemm_bt<0><<<256, 256, 0, stream>>>(Kb, Wqt + 1024 * 1024, Kbf, 4096, 1024, 1024, 8);
    gemm_bt<0><<<256, 256, 0, stream>>>(Kb, Wqt + 2 * 1024 * 1024, Vb, 4096, 1024, 1024, 8);

    kred_kernel<<<256, 256, 0, stream>>>(Kbf, krd);
    transpose_v<<<1024, 256, 0, stream>>>(Vb, Vt);

    // bqk overlays Sb/Kb — only now that the projection GEMMs are done.
    hipMemsetAsync(bqk, 0, (size_t)4 * 1024 * 1024 * 4, stream);
    scatter_bias<<<64, 256, 0, stream>>>(ab, embs, scal, bqk, 16384);

    attn_kernel<<<1024, 256, 0, stream>>>(Qb, Kbf, Vt, bqk, krd, masks, ctx);

    gemm_bt<1><<<256, 256, 0, stream>>>(ctx, Wot, d_out, 4096, 1024, 1024, 8);
}

// Round 2
// 269.530 us; speedup vs baseline: 1.1780x; 1.1780x over previous
//
#include <hip/hip_runtime.h>
#include <stdint.h>

// AttentionLayer_27599459844127 — round 1:
//  * attn_kernel v2: barrier-free, per-wave independent, direct-L2 gathers for
//    packed(mask|bias) + kred, per-wave-private LDS P tile only.
//  * packed mask/bias dword (bf16|bf16), built in-place over f32 bqk.
//  * QKV projection GEMMs fused into one 768-block launch (3 blocks/CU).

typedef __attribute__((ext_vector_type(8))) short short8;
typedef __attribute__((ext_vector_type(4))) float f32x4;
typedef __attribute__((ext_vector_type(4))) unsigned short ushort4v;
typedef __attribute__((ext_vector_type(4))) unsigned uint4v;

#define DEVI __device__ __forceinline__

constexpr float NEG_MIN = -3.4028234663852886e38f;
constexpr float LOG2E   = 1.4426950408889634f;

DEVI unsigned short f2b(float f) {
    union { float f; unsigned u; } x; x.f = f;
    unsigned u = x.u;
    unsigned r = (u + 0x7fffu + ((u >> 16) & 1u)) >> 16;  // RNE
    return (unsigned short)r;
}
DEVI float b2f(unsigned short b) {
    union { unsigned u; float f; } x; x.u = ((unsigned)b) << 16;
    return x.f;
}

// ---------------- cast f32 -> bf16 (vectorized) ----------------
__global__ void __launch_bounds__(256) cast_f32_bf16(const float* __restrict__ src,
                                                     unsigned short* __restrict__ dst, int n4) {
    int i = blockIdx.x * 256 + threadIdx.x;
    if (i >= n4) return;
    float4 v = reinterpret_cast<const float4*>(src)[i];
    ushort4v o;
    o.x = f2b(v.x); o.y = f2b(v.y); o.z = f2b(v.z); o.w = f2b(v.w);
    reinterpret_cast<ushort4v*>(dst)[i] = o;
}

// ---------------- transpose + cast: src f32 [R][C] -> dst bf16 [C][R] ----------------
__global__ void __launch_bounds__(256) transpose_cast(const float* __restrict__ src,
                                                      unsigned short* __restrict__ dst,
                                                      int R, int C) {
    __shared__ float t[64][65];
    int ctiles = C >> 6;
    int bc = blockIdx.x % ctiles, br = blockIdx.x / ctiles;
    int tid = threadIdx.x;
    int r0 = tid >> 4, c4 = (tid & 15) << 2;
    for (int i = 0; i < 4; ++i) {
        int row = r0 + i * 16;
        float4 v = *reinterpret_cast<const float4*>(&src[(size_t)(br * 64 + row) * C + bc * 64 + c4]);
        t[row][c4] = v.x; t[row][c4 + 1] = v.y; t[row][c4 + 2] = v.z; t[row][c4 + 3] = v.w;
    }
    __syncthreads();
    int cr0 = tid >> 4, r4 = (tid & 15) << 2;
    for (int i = 0; i < 4; ++i) {
        int crow = cr0 + i * 16;
        ushort4v o;
        o.x = f2b(t[r4][crow]); o.y = f2b(t[r4 + 1][crow]);
        o.z = f2b(t[r4 + 2][crow]); o.w = f2b(t[r4 + 3][crow]);
        *reinterpret_cast<ushort4v*>(&dst[(size_t)(bc * 64 + crow) * R + br * 64 + r4]) = o;
    }
}

// ---------------- shared 128x128 GEMM tile body: C = A[4096,1024] @ Bt[1024,1024]^T --------
template <int OUT_F32>
DEVI void gemm128_body(const unsigned short* __restrict__ A,
                       const unsigned short* __restrict__ Bt,
                       void* __restrict__ Cv, int bm, int bn,
                       unsigned short* As, unsigned short* Bs) {
    const int Kd = 1024, N = 1024;
    int tid = threadIdx.x, l = tid & 63, w = tid >> 6;
    int wm = w >> 1, wn = w & 1;
    int l15 = l & 15, koff = (l >> 4) << 3;
    f32x4 acc[4][4] = {};
    const int arow = tid >> 2, acol = (tid & 3) << 3;
    const unsigned short* Ab = A + (size_t)(bm * 128) * Kd;
    const unsigned short* Bb = Bt + (size_t)(bn * 128) * Kd;
    for (int kt = 0; kt < Kd; kt += 32) {
        short8 va0 = *reinterpret_cast<const short8*>(&Ab[(size_t)arow * Kd + kt + acol]);
        short8 va1 = *reinterpret_cast<const short8*>(&Ab[(size_t)(arow + 64) * Kd + kt + acol]);
        short8 vb0 = *reinterpret_cast<const short8*>(&Bb[(size_t)arow * Kd + kt + acol]);
        short8 vb1 = *reinterpret_cast<const short8*>(&Bb[(size_t)(arow + 64) * Kd + kt + acol]);
        __syncthreads();
        *reinterpret_cast<short8*>(&As[arow * 40 + acol]) = va0;
        *reinterpret_cast<short8*>(&As[(arow + 64) * 40 + acol]) = va1;
        *reinterpret_cast<short8*>(&Bs[arow * 40 + acol]) = vb0;
        *reinterpret_cast<short8*>(&Bs[(arow + 64) * 40 + acol]) = vb1;
        __syncthreads();
        short8 af[4], bf[4];
        for (int m = 0; m < 4; ++m)
            af[m] = *reinterpret_cast<const short8*>(&As[(wm * 64 + m * 16 + l15) * 40 + koff]);
        for (int n = 0; n < 4; ++n)
            bf[n] = *reinterpret_cast<const short8*>(&Bs[(wn * 64 + n * 16 + l15) * 40 + koff]);
        for (int m = 0; m < 4; ++m)
            for (int n = 0; n < 4; ++n)
                acc[m][n] = __builtin_amdgcn_mfma_f32_16x16x32_bf16(af[m], bf[n], acc[m][n], 0, 0, 0);
    }
    for (int m = 0; m < 4; ++m)
        for (int n = 0; n < 4; ++n)
            for (int r = 0; r < 4; ++r) {
                int row = bm * 128 + wm * 64 + m * 16 + ((l >> 4) << 2) + r;
                int col = bn * 128 + wn * 64 + n * 16 + l15;
                float v = acc[m][n][r];
                if (OUT_F32) reinterpret_cast<float*>(Cv)[(size_t)row * N + col] = v;
                else reinterpret_cast<unsigned short*>(Cv)[(size_t)row * N + col] = f2b(v);
            }
}

// fused Q/K/V projection: grid = 768 blocks, g = which GEMM
__global__ void __launch_bounds__(256) gemm_qkv(const unsigned short* __restrict__ Sb,
                                                const unsigned short* __restrict__ Kb,
                                                const unsigned short* __restrict__ W3,
                                                unsigned short* __restrict__ Qb,
                                                unsigned short* __restrict__ Kbf,
                                                unsigned short* __restrict__ Vb) {
    __shared__ unsigned short As[128 * 40];
    __shared__ unsigned short Bs[128 * 40];
    int g = blockIdx.x >> 8, sub = blockIdx.x & 255;
    const unsigned short* A = (g == 0) ? Sb : Kb;
    const unsigned short* Bt = W3 + (size_t)g * (1024 * 1024);
    unsigned short* C = (g == 0) ? Qb : ((g == 1) ? Kbf : Vb);
    gemm128_body<0>(A, Bt, C, sub >> 3, sub & 7, As, Bs);
}

__global__ void __launch_bounds__(256) gemm_wo(const unsigned short* __restrict__ A,
                                               const unsigned short* __restrict__ Bt,
                                               float* __restrict__ C) {
    __shared__ unsigned short As[128 * 40];
    __shared__ unsigned short Bs[128 * 40];
    gemm128_body<1>(A, Bt, C, blockIdx.x >> 3, blockIdx.x & 7, As, Bs);
}

// ---------------- k_red[b,s,h] = sum_a K[b,s,h,a] ----------------
__global__ void __launch_bounds__(256) kred_kernel(const unsigned short* __restrict__ K,
                                                   float* __restrict__ kred) {
    int idx = blockIdx.x * 256 + threadIdx.x;  // B*S*H = 65536
    const unsigned short* p = K + (size_t)idx * 64;
    float s = 0.f;
    for (int c = 0; c < 8; ++c) {
        short8 v = *reinterpret_cast<const short8*>(&p[c * 8]);
        for (int j = 0; j < 8; ++j) s += b2f((unsigned short)v[j]);
    }
    kred[idx] = s;
}

// ---------------- V [B,S,H,DH] -> Vt [B,H,DH,S] (bf16) ----------------
__global__ void __launch_bounds__(256) transpose_v(const unsigned short* __restrict__ V,
                                                   unsigned short* __restrict__ Vt) {
    __shared__ unsigned short t[64][66];
    int bid = blockIdx.x;
    int st = bid & 15, h = (bid >> 4) & 15, b = bid >> 8;
    int tid = threadIdx.x;
    int s = tid >> 2, c16 = (tid & 3) << 4;
    const unsigned short* src = V + ((size_t)((b * 1024 + st * 64 + s) * 16 + h)) * 64 + c16;
    short8 v0 = *reinterpret_cast<const short8*>(src);
    short8 v1 = *reinterpret_cast<const short8*>(src + 8);
    for (int j = 0; j < 8; ++j) {
        t[s][c16 + j] = (unsigned short)v0[j];
        t[s][c16 + 8 + j] = (unsigned short)v1[j];
    }
    __syncthreads();
    int a = tid >> 2, s16 = (tid & 3) << 4;
    short8 o0, o1;
    for (int j = 0; j < 8; ++j) {
        o0[j] = (short)t[s16 + j][a];
        o1[j] = (short)t[s16 + 8 + j][a];
    }
    unsigned short* dst = Vt + ((size_t)((b * 16 + h) * 64 + a)) * 1024 + st * 64 + s16;
    *reinterpret_cast<short8*>(dst) = o0;
    *reinterpret_cast<short8*>(dst + 8) = o1;
}

// ---------------- sparse bias scatter: bqk[b,q,k] += embs[e]·scal ----------------
__global__ void __launch_bounds__(256) scatter_bias(const int* __restrict__ ab,
                                                    const float* __restrict__ embs,
                                                    const float* __restrict__ scal,
                                                    float* __restrict__ bqk, int n) {
    int i = blockIdx.x * 256 + threadIdx.x;
    if (i >= n) return;
    int b = ab[i * 4], q = ab[i * 4 + 1], k = ab[i * 4 + 2], e = ab[i * 4 + 3];
    float v = 0.f;
    for (int a = 0; a < 64; ++a) v += embs[e * 64 + a] * scal[a];
    atomicAdd(&bqk[((size_t)b * 1024 + q) * 1024 + k], v);
}

// ---------------- pack (mask, bqk f32) -> dword (bf16(mask)<<16 | bf16(bqk)), in place ----
__global__ void __launch_bounds__(256) pack_mb(const float* __restrict__ masks,
                                               unsigned* __restrict__ pk, int n4) {
    int i = blockIdx.x * 256 + threadIdx.x;
    if (i >= n4) return;
    float4 m = reinterpret_cast<const float4*>(masks)[i];
    float4 bv = reinterpret_cast<const float4*>(pk)[i];  // aliases f32 bqk
    uint4v o;
    o.x = ((unsigned)f2b(m.x) << 16) | f2b(bv.x);
    o.y = ((unsigned)f2b(m.y) << 16) | f2b(bv.y);
    o.z = ((unsigned)f2b(m.z) << 16) | f2b(bv.z);
    o.w = ((unsigned)f2b(m.w) << 16) | f2b(bv.w);
    reinterpret_cast<uint4v*>(pk)[i] = o;
}

// ---------------- fused attention v2: barrier-free, per-wave independent ----------------
// grid = B*(S/16)*4 hgroups; block = 4 waves; wave w -> head hg*4+w, same 16 q-rows.
__global__ void __launch_bounds__(256) attn_kernel(const unsigned short* __restrict__ Q,
                                                   const unsigned short* __restrict__ K,
                                                   const unsigned short* __restrict__ Vt,
                                                   const unsigned* __restrict__ pk,
                                                   const float* __restrict__ kred,
                                                   unsigned short* __restrict__ ctx) {
    __shared__ unsigned short p_s[4][16][72];  // per-wave-private P tile

    int bid = blockIdx.x;
    int hg = bid & 3, qt = (bid >> 2) & 63, b = bid >> 8;
    int tid = threadIdx.x, w = tid >> 6, l = tid & 63;
    int h = hg * 4 + w;
    int qbase = qt * 16;
    int l15 = l & 15, l16 = l >> 4;
    int koff = l16 << 3;

    short8 qf0, qf1;
    {
        const unsigned short* qp = Q + ((size_t)((b * 1024 + qbase + l15) * 16 + h)) * 64 + koff;
        qf0 = *reinterpret_cast<const short8*>(qp);
        qf1 = *reinterpret_cast<const short8*>(qp + 32);
    }
    const unsigned* pkp = pk + (size_t)(b * 1024 + qbase) * 1024;
    const float* krp = kred + (size_t)b * 1024 * 16 + h;
    const unsigned short* Kp = K + (size_t)b * 1024 * 1024 + h * 64 + koff;  // row stride 1024 shorts
    const unsigned short* Vp = Vt + ((size_t)(b * 16 + h) * 64) * 1024;

    float m_r[4], l_r[4];
    f32x4 O[4] = {};
    for (int r = 0; r < 4; ++r) { m_r[r] = -INFINITY; l_r[r] = 0.f; }

    for (int kt = 0; kt < 16; ++kt) {
        int kbase = kt * 64;

        // issue all L2 gathers up front (bias|mask packed + kred)
        float krv[4];
        unsigned pkv[4][4];
#pragma unroll
        for (int n = 0; n < 4; ++n) {
            int col = kbase + n * 16 + l15;
            krv[n] = krp[(size_t)col * 16];
#pragma unroll
            for (int r = 0; r < 4; ++r)
                pkv[n][r] = pkp[(size_t)(l16 * 4 + r) * 1024 + col];
        }

        // QK^T
        f32x4 sacc[4] = {};
#pragma unroll
        for (int n = 0; n < 4; ++n) {
            const unsigned short* kp = Kp + (size_t)(kbase + n * 16 + l15) * 1024;
            short8 kf0 = *reinterpret_cast<const short8*>(kp);
            short8 kf1 = *reinterpret_cast<const short8*>(kp + 32);
            sacc[n] = __builtin_amdgcn_mfma_f32_16x16x32_bf16(qf0, kf0, sacc[n], 0, 0, 0);
            sacc[n] = __builtin_amdgcn_mfma_f32_16x16x32_bf16(qf1, kf1, sacc[n], 0, 0, 0);
        }

        // logits = (qk + bias*kred)*rsqrt(DH), mask
        float logit[4][4], tmax[4];
        for (int r = 0; r < 4; ++r) tmax[r] = -INFINITY;
#pragma unroll
        for (int n = 0; n < 4; ++n) {
#pragma unroll
            for (int r = 0; r < 4; ++r) {
                float mv = b2f((unsigned short)(pkv[n][r] >> 16));
                float bq = b2f((unsigned short)(pkv[n][r] & 0xffffu));
                float sv = (sacc[n][r] + bq * krv[n]) * 0.125f;
                float lg = sv * mv + (1.f - ceilf(mv)) * NEG_MIN;
                logit[n][r] = lg;
                tmax[r] = fmaxf(tmax[r], lg);
            }
        }
#pragma unroll
        for (int d = 1; d < 16; d <<= 1)
#pragma unroll
            for (int r = 0; r < 4; ++r) tmax[r] = fmaxf(tmax[r], __shfl_xor(tmax[r], d));

        float alpha[4], psum[4];
#pragma unroll
        for (int r = 0; r < 4; ++r) {
            float nm = fmaxf(m_r[r], tmax[r]);
            alpha[r] = exp2f((m_r[r] - nm) * LOG2E);
            m_r[r] = nm;
            psum[r] = 0.f;
        }
#pragma unroll
        for (int n = 0; n < 4; ++n) {
#pragma unroll
            for (int r = 0; r < 4; ++r) {
                float p = exp2f((logit[n][r] - m_r[r]) * LOG2E);
                psum[r] += p;
                float mv = b2f((unsigned short)(pkv[n][r] >> 16));
                p_s[w][l16 * 4 + r][n * 16 + l15] = f2b(p * mv);
            }
        }
#pragma unroll
        for (int d = 1; d < 16; d <<= 1)
#pragma unroll
            for (int r = 0; r < 4; ++r) psum[r] += __shfl_xor(psum[r], d);
#pragma unroll
        for (int r = 0; r < 4; ++r) l_r[r] = l_r[r] * alpha[r] + psum[r];
#pragma unroll
        for (int af = 0; af < 4; ++af)
#pragma unroll
            for (int r = 0; r < 4; ++r) O[af][r] *= alpha[r];

        // PV (A = per-wave P tile in LDS, B = Vt rows; same-wave LDS -> no barrier)
#pragma unroll
        for (int ks = 0; ks < 2; ++ks) {
            short8 pa = *reinterpret_cast<const short8*>(&p_s[w][l15][ks * 32 + koff]);
#pragma unroll
            for (int af = 0; af < 4; ++af) {
                short8 vb = *reinterpret_cast<const short8*>(
                    Vp + (size_t)(af * 16 + l15) * 1024 + kbase + ks * 32 + koff);
                O[af] = __builtin_amdgcn_mfma_f32_16x16x32_bf16(pa, vb, O[af], 0, 0, 0);
            }
        }
    }

    for (int af = 0; af < 4; ++af)
        for (int r = 0; r < 4; ++r) {
            int row = l16 * 4 + r;
            float v = O[af][r] / l_r[r];
            ctx[((size_t)((b * 1024 + qbase + row) * 16 + h)) * 64 + af * 16 + l15] = f2b(v);
        }
}

// ---------------- host launch ----------------
extern "C" void kernel_launch(void* const* d_in, const int* in_sizes, int n_in,
                              void* d_out, int out_size, void* d_ws, size_t ws_size,
                              hipStream_t stream) {
    const float* states     = (const float*)d_in[0];
    const float* key_states = (const float*)d_in[1];
    const float* masks      = (const float*)d_in[2];
    const int*   ab         = (const int*)d_in[3];
    const float* Wq         = (const float*)d_in[4];
    const float* Wk         = (const float*)d_in[5];
    const float* Wv         = (const float*)d_in[6];
    const float* Wo         = (const float*)d_in[7];
    const float* embs       = (const float*)d_in[8];
    const float* scal       = (const float*)d_in[9];

    char* ws = (char*)d_ws;
    const size_t MB = 1024 * 1024;
    unsigned short* Sb  = (unsigned short*)(ws);
    unsigned short* Kb  = (unsigned short*)(ws + 8 * MB);
    float*          bqk = (float*)(ws);                     // overlays Sb/Kb after QKV GEMM
    unsigned short* Wqt = (unsigned short*)(ws + 16 * MB);  // Wq^T,Wk^T,Wv^T contiguous (6MB)
    unsigned short* Wot = (unsigned short*)(ws + 22 * MB);
    unsigned short* Qb  = (unsigned short*)(ws + 24 * MB);
    unsigned short* Kbf = (unsigned short*)(ws + 32 * MB);
    unsigned short* Vb  = (unsigned short*)(ws + 40 * MB);  // dead after transpose_v
    unsigned short* ctx = (unsigned short*)(ws + 40 * MB);  // reuses Vb region
    unsigned short* Vt  = (unsigned short*)(ws + 48 * MB);
    float*          krd = (float*)(ws + 56 * MB);           // 256KB
    (void)in_sizes; (void)n_in; (void)out_size; (void)ws_size;

    cast_f32_bf16<<<4096, 256, 0, stream>>>(states, Sb, 1024 * 1024);
    cast_f32_bf16<<<4096, 256, 0, stream>>>(key_states, Kb, 1024 * 1024);
    transpose_cast<<<256, 256, 0, stream>>>(Wq, Wqt, 1024, 1024);
    transpose_cast<<<256, 256, 0, stream>>>(Wk, Wqt + 1024 * 1024, 1024, 1024);
    transpose_cast<<<256, 256, 0, stream>>>(Wv, Wqt + 2 * 1024 * 1024, 1024, 1024);
    transpose_cast<<<256, 256, 0, stream>>>(Wo, Wot, 1024, 1024);

    gemm_qkv<<<768, 256, 0, stream>>>(Sb, Kb, Wqt, Qb, Kbf, Vb);

    kred_kernel<<<256, 256, 0, stream>>>(Kbf, krd);
    transpose_v<<<1024, 256, 0, stream>>>(Vb, Vt);

    // bqk overlays Sb/Kb — safe only after gemm_qkv has consumed them (stream order).
    hipMemsetAsync(bqk, 0, (size_t)4 * 1024 * 1024 * 4, stream);
    scatter_bias<<<64, 256, 0, stream>>>(ab, embs, scal, bqk, 16384);
    pack_mb<<<4096, 256, 0, stream>>>(masks, (unsigned*)bqk, 1024 * 1024);

    attn_kernel<<<1024, 256, 0, stream>>>(Qb, Kbf, Vt, (const unsigned*)bqk, krd, ctx);

    gemm_wo<<<256, 256, 0, stream>>>(ctx, Wot, (float*)d_out);
}

// Round 3
// 255.879 us; speedup vs baseline: 1.2408x; 1.0534x over previous
//
#include <hip/hip_runtime.h>
#include <stdint.h>

// AttentionLayer_27599459844127 — round 2:
//  * attn v3: swapped QK^T (C[k][q]) -> in-lane softmax reductions (2 shfl instead
//    of 16), b64 P-stores, per-lane scalar m/l state.
//  * rotating single-buffer register pipeline: K/pk for tile t+1 issued right
//    after tile t consumes them; V issued at tile top, used at tile end.
//  * transposed ancillaries: bqkT/pkT [b][k][q] (scatter+pack), kredT [b][h][s].

typedef __attribute__((ext_vector_type(8))) short short8;
typedef __attribute__((ext_vector_type(4))) float f32x4;
typedef __attribute__((ext_vector_type(4))) unsigned short ushort4v;
typedef __attribute__((ext_vector_type(2))) unsigned uint2v;
typedef __attribute__((ext_vector_type(4))) unsigned uint4v;

#define DEVI __device__ __forceinline__

constexpr float NEG_MIN = -3.4028234663852886e38f;
constexpr float LOG2E   = 1.4426950408889634f;

DEVI unsigned short f2b(float f) {
    union { float f; unsigned u; } x; x.f = f;
    unsigned u = x.u;
    unsigned r = (u + 0x7fffu + ((u >> 16) & 1u)) >> 16;  // RNE
    return (unsigned short)r;
}
DEVI float hi_as_f(unsigned p) { union { unsigned u; float f; } x; x.u = p & 0xffff0000u; return x.f; }
DEVI float lo_as_f(unsigned p) { union { unsigned u; float f; } x; x.u = p << 16; return x.f; }
DEVI float b2f(unsigned short b) { union { unsigned u; float f; } x; x.u = ((unsigned)b) << 16; return x.f; }

// ---------------- cast f32 -> bf16 (vectorized) ----------------
__global__ void __launch_bounds__(256) cast_f32_bf16(const float* __restrict__ src,
                                                     unsigned short* __restrict__ dst, int n4) {
    int i = blockIdx.x * 256 + threadIdx.x;
    if (i >= n4) return;
    float4 v = reinterpret_cast<const float4*>(src)[i];
    ushort4v o;
    o.x = f2b(v.x); o.y = f2b(v.y); o.z = f2b(v.z); o.w = f2b(v.w);
    reinterpret_cast<ushort4v*>(dst)[i] = o;
}

// ---------------- transpose + cast: src f32 [R][C] -> dst bf16 [C][R] ----------------
__global__ void __launch_bounds__(256) transpose_cast(const float* __restrict__ src,
                                                      unsigned short* __restrict__ dst,
                                                      int R, int C) {
    __shared__ float t[64][65];
    int ctiles = C >> 6;
    int bc = blockIdx.x % ctiles, br = blockIdx.x / ctiles;
    int tid = threadIdx.x;
    int r0 = tid >> 4, c4 = (tid & 15) << 2;
    for (int i = 0; i < 4; ++i) {
        int row = r0 + i * 16;
        float4 v = *reinterpret_cast<const float4*>(&src[(size_t)(br * 64 + row) * C + bc * 64 + c4]);
        t[row][c4] = v.x; t[row][c4 + 1] = v.y; t[row][c4 + 2] = v.z; t[row][c4 + 3] = v.w;
    }
    __syncthreads();
    int cr0 = tid >> 4, r4 = (tid & 15) << 2;
    for (int i = 0; i < 4; ++i) {
        int crow = cr0 + i * 16;
        ushort4v o;
        o.x = f2b(t[r4][crow]); o.y = f2b(t[r4 + 1][crow]);
        o.z = f2b(t[r4 + 2][crow]); o.w = f2b(t[r4 + 3][crow]);
        *reinterpret_cast<ushort4v*>(&dst[(size_t)(bc * 64 + crow) * R + br * 64 + r4]) = o;
    }
}

// ---------------- shared 128x128 GEMM tile body ----------------
template <int OUT_F32>
DEVI void gemm128_body(const unsigned short* __restrict__ A,
                       const unsigned short* __restrict__ Bt,
                       void* __restrict__ Cv, int bm, int bn,
                       unsigned short* As, unsigned short* Bs) {
    const int Kd = 1024, N = 1024;
    int tid = threadIdx.x, l = tid & 63, w = tid >> 6;
    int wm = w >> 1, wn = w & 1;
    int l15 = l & 15, koff = (l >> 4) << 3;
    f32x4 acc[4][4] = {};
    const int arow = tid >> 2, acol = (tid & 3) << 3;
    const unsigned short* Ab = A + (size_t)(bm * 128) * Kd;
    const unsigned short* Bb = Bt + (size_t)(bn * 128) * Kd;
    for (int kt = 0; kt < Kd; kt += 32) {
        short8 va0 = *reinterpret_cast<const short8*>(&Ab[(size_t)arow * Kd + kt + acol]);
        short8 va1 = *reinterpret_cast<const short8*>(&Ab[(size_t)(arow + 64) * Kd + kt + acol]);
        short8 vb0 = *reinterpret_cast<const short8*>(&Bb[(size_t)arow * Kd + kt + acol]);
        short8 vb1 = *reinterpret_cast<const short8*>(&Bb[(size_t)(arow + 64) * Kd + kt + acol]);
        __syncthreads();
        *reinterpret_cast<short8*>(&As[arow * 40 + acol]) = va0;
        *reinterpret_cast<short8*>(&As[(arow + 64) * 40 + acol]) = va1;
        *reinterpret_cast<short8*>(&Bs[arow * 40 + acol]) = vb0;
        *reinterpret_cast<short8*>(&Bs[(arow + 64) * 40 + acol]) = vb1;
        __syncthreads();
        short8 af[4], bf[4];
        for (int m = 0; m < 4; ++m)
            af[m] = *reinterpret_cast<const short8*>(&As[(wm * 64 + m * 16 + l15) * 40 + koff]);
        for (int n = 0; n < 4; ++n)
            bf[n] = *reinterpret_cast<const short8*>(&Bs[(wn * 64 + n * 16 + l15) * 40 + koff]);
        for (int m = 0; m < 4; ++m)
            for (int n = 0; n < 4; ++n)
                acc[m][n] = __builtin_amdgcn_mfma_f32_16x16x32_bf16(af[m], bf[n], acc[m][n], 0, 0, 0);
    }
    for (int m = 0; m < 4; ++m)
        for (int n = 0; n < 4; ++n)
            for (int r = 0; r < 4; ++r) {
                int row = bm * 128 + wm * 64 + m * 16 + ((l >> 4) << 2) + r;
                int col = bn * 128 + wn * 64 + n * 16 + l15;
                float v = acc[m][n][r];
                if (OUT_F32) reinterpret_cast<float*>(Cv)[(size_t)row * N + col] = v;
                else reinterpret_cast<unsigned short*>(Cv)[(size_t)row * N + col] = f2b(v);
            }
}

__global__ void __launch_bounds__(256) gemm_qkv(const unsigned short* __restrict__ Sb,
                                                const unsigned short* __restrict__ Kb,
                                                const unsigned short* __restrict__ W3,
                                                unsigned short* __restrict__ Qb,
                                                unsigned short* __restrict__ Kbf,
                                                unsigned short* __restrict__ Vb) {
    __shared__ unsigned short As[128 * 40];
    __shared__ unsigned short Bs[128 * 40];
    int g = blockIdx.x >> 8, sub = blockIdx.x & 255;
    const unsigned short* A = (g == 0) ? Sb : Kb;
    const unsigned short* Bt = W3 + (size_t)g * (1024 * 1024);
    unsigned short* C = (g == 0) ? Qb : ((g == 1) ? Kbf : Vb);
    gemm128_body<0>(A, Bt, C, sub >> 3, sub & 7, As, Bs);
}

__global__ void __launch_bounds__(256) gemm_wo(const unsigned short* __restrict__ A,
                                               const unsigned short* __restrict__ Bt,
                                               float* __restrict__ C) {
    __shared__ unsigned short As[128 * 40];
    __shared__ unsigned short Bs[128 * 40];
    gemm128_body<1>(A, Bt, C, blockIdx.x >> 3, blockIdx.x & 7, As, Bs);
}

// ---------------- kredT[b][h][s] = sum_a K[b,s,h,a] ----------------
__global__ void __launch_bounds__(256) kred_kernel(const unsigned short* __restrict__ K,
                                                   float* __restrict__ kredT) {
    int idx = blockIdx.x * 256 + threadIdx.x;  // over (b,s,h)
    const unsigned short* p = K + (size_t)idx * 64;
    float s = 0.f;
    for (int c = 0; c < 8; ++c) {
        short8 v = *reinterpret_cast<const short8*>(&p[c * 8]);
        for (int j = 0; j < 8; ++j) s += b2f((unsigned short)v[j]);
    }
    int b = idx >> 14, ss = (idx >> 4) & 1023, h = idx & 15;
    kredT[((size_t)(b * 16 + h) << 10) + ss] = s;
}

// ---------------- V [B,S,H,DH] -> Vt [B,H,DH,S] (bf16) ----------------
__global__ void __launch_bounds__(256) transpose_v(const unsigned short* __restrict__ V,
                                                   unsigned short* __restrict__ Vt) {
    __shared__ unsigned short t[64][66];
    int bid = blockIdx.x;
    int st = bid & 15, h = (bid >> 4) & 15, b = bid >> 8;
    int tid = threadIdx.x;
    int s = tid >> 2, c16 = (tid & 3) << 4;
    const unsigned short* src = V + ((size_t)((b * 1024 + st * 64 + s) * 16 + h)) * 64 + c16;
    short8 v0 = *reinterpret_cast<const short8*>(src);
    short8 v1 = *reinterpret_cast<const short8*>(src + 8);
    for (int j = 0; j < 8; ++j) {
        t[s][c16 + j] = (unsigned short)v0[j];
        t[s][c16 + 8 + j] = (unsigned short)v1[j];
    }
    __syncthreads();
    int a = tid >> 2, s16 = (tid & 3) << 4;
    short8 o0, o1;
    for (int j = 0; j < 8; ++j) {
        o0[j] = (short)t[s16 + j][a];
        o1[j] = (short)t[s16 + 8 + j][a];
    }
    unsigned short* dst = Vt + ((size_t)((b * 16 + h) * 64 + a)) * 1024 + st * 64 + s16;
    *reinterpret_cast<short8*>(dst) = o0;
    *reinterpret_cast<short8*>(dst + 8) = o1;
}

// ---------------- sparse bias scatter (TRANSPOSED): bqkT[b][k][q] += embs[e]·scal ----------
__global__ void __launch_bounds__(256) scatter_bias(const int* __restrict__ ab,
                                                    const float* __restrict__ embs,
                                                    const float* __restrict__ scal,
                                                    float* __restrict__ bqkT, int n) {
    int i = blockIdx.x * 256 + threadIdx.x;
    if (i >= n) return;
    int b = ab[i * 4], q = ab[i * 4 + 1], k = ab[i * 4 + 2], e = ab[i * 4 + 3];
    float v = 0.f;
    for (int a = 0; a < 64; ++a) v += embs[e * 64 + a] * scal[a];
    atomicAdd(&bqkT[((size_t)b * 1024 + k) * 1024 + q], v);
}

// ---------------- pack_T: pkT[b][k][q] = bf16(mask[b,q,k])<<16 | bf16(bqkT[b][k][q]) --------
// in-place over bqkT; mask transposed through LDS. grid = 4*16*16, 64x64 tiles.
__global__ void __launch_bounds__(256) pack_T(const float* __restrict__ masks,
                                              unsigned* __restrict__ pkT) {
    __shared__ float mt[64][65];
    int bid = blockIdx.x;
    int qt = bid & 15, ktile = (bid >> 4) & 15, b = bid >> 8;
    int tid = threadIdx.x;
    int row = tid >> 2, c16 = (tid & 3) << 4;
    // load mask tile rows (q-major, coalesced)
    const float* mrow = masks + ((size_t)(b * 1024 + qt * 64 + row)) * 1024 + ktile * 64 + c16;
    for (int j = 0; j < 16; j += 4) {
        float4 v = *reinterpret_cast<const float4*>(mrow + j);
        mt[row][c16 + j] = v.x; mt[row][c16 + j + 1] = v.y;
        mt[row][c16 + j + 2] = v.z; mt[row][c16 + j + 3] = v.w;
    }
    __syncthreads();
    // output rows (k-major, coalesced), mask from transposed LDS
    unsigned* orow = pkT + ((size_t)(b * 1024 + ktile * 64 + row)) * 1024 + qt * 64 + c16;
    for (int j = 0; j < 16; j += 4) {
        float4 bv = *reinterpret_cast<const float4*>(reinterpret_cast<float*>(orow + j));
        uint4v o;
        o.x = ((unsigned)f2b(mt[c16 + j][row]) << 16)     | f2b(bv.x);
        o.y = ((unsigned)f2b(mt[c16 + j + 1][row]) << 16) | f2b(bv.y);
        o.z = ((unsigned)f2b(mt[c16 + j + 2][row]) << 16) | f2b(bv.z);
        o.w = ((unsigned)f2b(mt[c16 + j + 3][row]) << 16) | f2b(bv.w);
        *reinterpret_cast<uint4v*>(orow + j) = o;
    }
}

// ---------------- fused attention v3: swapped QK^T + register pipeline ----------------
// grid = B*(S/16)*4 hgroups; block = 4 waves; wave w -> head hg*4+w, 16 q-rows.
__global__ void __launch_bounds__(256, 3) attn_kernel(const unsigned short* __restrict__ Q,
                                                      const unsigned short* __restrict__ K,
                                                      const unsigned short* __restrict__ Vt,
                                                      const unsigned* __restrict__ pkT,
                                                      const float* __restrict__ kredT,
                                                      unsigned short* __restrict__ ctx) {
    __shared__ __align__(16) unsigned short p_s[4][16][72];  // per-wave-private P tile

    int bid = blockIdx.x;
    int hg = bid & 3, qt = (bid >> 2) & 63, b = bid >> 8;
    int tid = threadIdx.x, w = tid >> 6, l = tid & 63;
    int h = hg * 4 + w;
    int qbase = qt * 16;
    int l15 = l & 15, l16 = l >> 4;
    int koff = l16 << 3;

    // Q fragments (B-operand: lane l15 -> q column)
    short8 qf0, qf1;
    {
        const unsigned short* qp = Q + ((size_t)((b * 1024 + qbase + l15) * 16 + h)) * 64 + koff;
        qf0 = *reinterpret_cast<const short8*>(qp);
        qf1 = *reinterpret_cast<const short8*>(qp + 32);
    }
    const unsigned* pkp = pkT + ((size_t)b << 20) + qbase + l15;          // + k*1024
    const float* krp = kredT + ((size_t)(b * 16 + h) << 10);              // + k
    const unsigned short* Kp = K + ((size_t)b << 20) + h * 64 + koff;     // + s*1024
    const unsigned short* Vp = Vt + ((size_t)(b * 16 + h) << 16);         // + d*1024 + s

    float m_r = -INFINITY, l_r = 0.f;  // per-lane scalars (q = qbase + l15)
    f32x4 O[4] = {};

    // rotating single-buffer pipeline registers
    short8 kf[8];      // A-operand K frags for current tile
    unsigned pkv[16];  // packed mask|bias for current tile

#pragma unroll
    for (int n = 0; n < 4; ++n) {
        const unsigned short* kp = Kp + ((size_t)(n * 16 + l15) << 10);
        kf[n * 2] = *reinterpret_cast<const short8*>(kp);
        kf[n * 2 + 1] = *reinterpret_cast<const short8*>(kp + 32);
#pragma unroll
        for (int r = 0; r < 4; ++r)
            pkv[n * 4 + r] = pkp[(size_t)(n * 16 + l16 * 4 + r) << 10];
    }

    for (int kt = 0; kt < 16; ++kt) {
        int kbase = kt * 64;

        // V loads for this tile (consumed at tile end — covered by QK+softmax)
        short8 vf[8];
#pragma unroll
        for (int ks = 0; ks < 2; ++ks)
#pragma unroll
            for (int af = 0; af < 4; ++af)
                vf[ks * 4 + af] = *reinterpret_cast<const short8*>(
                    Vp + ((size_t)(af * 16 + l15) << 10) + kbase + ks * 32 + koff);

        // QK^T swapped: C[row=k][col=q]
        f32x4 sacc[4] = {};
#pragma unroll
        for (int n = 0; n < 4; ++n) {
            sacc[n] = __builtin_amdgcn_mfma_f32_16x16x32_bf16(kf[n * 2], qf0, sacc[n], 0, 0, 0);
            sacc[n] = __builtin_amdgcn_mfma_f32_16x16x32_bf16(kf[n * 2 + 1], qf1, sacc[n], 0, 0, 0);
        }
        // K regs now dead -> issue next tile's K loads (in flight across softmax+PV)
        if (kt < 15) {
#pragma unroll
            for (int n = 0; n < 4; ++n) {
                const unsigned short* kp = Kp + ((size_t)(kbase + 64 + n * 16 + l15) << 10);
                kf[n * 2] = *reinterpret_cast<const short8*>(kp);
                kf[n * 2 + 1] = *reinterpret_cast<const short8*>(kp + 32);
            }
        }

        // logits (per lane: 16 k-values for q = l15)
        float lg[16];
        float tmax = -INFINITY;
#pragma unroll
        for (int n = 0; n < 4; ++n)
#pragma unroll
            for (int r = 0; r < 4; ++r) {
                int i = n * 4 + r;
                float mv = hi_as_f(pkv[i]);
                float bq = lo_as_f(pkv[i]);
                float krv = krp[kbase + n * 16 + l16 * 4 + r];
                float sv = fmaf(bq, krv, sacc[n][r]) * 0.125f;
                float v = sv * mv;
                if (!(mv > 0.f)) v += NEG_MIN;
                lg[i] = v;
                tmax = fmaxf(tmax, v);
            }
        // pk regs consumed -> issue next tile's gathers
        float mvs[16];
#pragma unroll
        for (int i = 0; i < 16; ++i) mvs[i] = hi_as_f(pkv[i]);
        if (kt < 15) {
#pragma unroll
            for (int n = 0; n < 4; ++n)
#pragma unroll
                for (int r = 0; r < 4; ++r)
                    pkv[n * 4 + r] = pkp[(size_t)(kbase + 64 + n * 16 + l16 * 4 + r) << 10];
        }

        // cross-lane max over the 4 l16 groups (same q)
        tmax = fmaxf(tmax, __shfl_xor(tmax, 16));
        tmax = fmaxf(tmax, __shfl_xor(tmax, 32));
        float nm = fmaxf(m_r, tmax);
        float al = exp2f((m_r - nm) * LOG2E);
        m_r = nm;

        // P = exp(lg - m); store masked bf16 pairs to LDS; sum unmasked
        float ps = 0.f;
#pragma unroll
        for (int n = 0; n < 4; ++n) {
            float p0 = exp2f((lg[n * 4 + 0] - m_r) * LOG2E);
            float p1 = exp2f((lg[n * 4 + 1] - m_r) * LOG2E);
            float p2 = exp2f((lg[n * 4 + 2] - m_r) * LOG2E);
            float p3 = exp2f((lg[n * 4 + 3] - m_r) * LOG2E);
            ps += (p0 + p1) + (p2 + p3);
            uint2v pk2;
            pk2.x = (unsigned)f2b(p0 * mvs[n * 4 + 0]) | ((unsigned)f2b(p1 * mvs[n * 4 + 1]) << 16);
            pk2.y = (unsigned)f2b(p2 * mvs[n * 4 + 2]) | ((unsigned)f2b(p3 * mvs[n * 4 + 3]) << 16);
            *reinterpret_cast<uint2v*>(&p_s[w][l15][n * 16 + (l16 << 2)]) = pk2;
        }
        ps += __shfl_xor(ps, 16);
        ps += __shfl_xor(ps, 32);
        l_r = l_r * al + ps;

        // redistribute alpha to O-row layout (O row q = l16*4+r)
        float alr[4];
#pragma unroll
        for (int r = 0; r < 4; ++r) alr[r] = __shfl(al, l16 * 4 + r);
#pragma unroll
        for (int af = 0; af < 4; ++af)
#pragma unroll
            for (int r = 0; r < 4; ++r) O[af][r] *= alr[r];

        // PV: A = P tile (same-wave LDS), B = V rows
#pragma unroll
        for (int ks = 0; ks < 2; ++ks) {
            short8 pa = *reinterpret_cast<const short8*>(&p_s[w][l15][ks * 32 + koff]);
#pragma unroll
            for (int af = 0; af < 4; ++af)
                O[af] = __builtin_amdgcn_mfma_f32_16x16x32_bf16(pa, vf[ks * 4 + af], O[af], 0, 0, 0);
        }
    }

    float llr[4];
#pragma unroll
    for (int r = 0; r < 4; ++r) llr[r] = __shfl(l_r, l16 * 4 + r);
#pragma unroll
    for (int af = 0; af < 4; ++af)
#pragma unroll
        for (int r = 0; r < 4; ++r) {
            int row = l16 * 4 + r;
            float v = O[af][r] / llr[r];
            ctx[((size_t)((b * 1024 + qbase + row) * 16 + h)) * 64 + af * 16 + l15] = f2b(v);
        }
}

// ---------------- host launch ----------------
extern "C" void kernel_launch(void* const* d_in, const int* in_sizes, int n_in,
                              void* d_out, int out_size, void* d_ws, size_t ws_size,
                              hipStream_t stream) {
    const float* states     = (const float*)d_in[0];
    const float* key_states = (const float*)d_in[1];
    const float* masks      = (const float*)d_in[2];
    const int*   ab         = (const int*)d_in[3];
    const float* Wq         = (const float*)d_in[4];
    const float* Wk         = (const float*)d_in[5];
    const float* Wv         = (const float*)d_in[6];
    const float* Wo         = (const float*)d_in[7];
    const float* embs       = (const float*)d_in[8];
    const float* scal       = (const float*)d_in[9];

    char* ws = (char*)d_ws;
    const size_t MB = 1024 * 1024;
    unsigned short* Sb   = (unsigned short*)(ws);
    unsigned short* Kb   = (unsigned short*)(ws + 8 * MB);
    float*          bqkT = (float*)(ws);                     // overlays Sb/Kb after QKV GEMM
    unsigned short* Wqt  = (unsigned short*)(ws + 16 * MB);  // Wq^T,Wk^T,Wv^T (6MB)
    unsigned short* Wot  = (unsigned short*)(ws + 22 * MB);
    unsigned short* Qb   = (unsigned short*)(ws + 24 * MB);
    unsigned short* Kbf  = (unsigned short*)(ws + 32 * MB);
    unsigned short* Vb   = (unsigned short*)(ws + 40 * MB);  // dead after transpose_v
    unsigned short* ctx  = (unsigned short*)(ws + 40 * MB);  // reuses Vb region
    unsigned short* Vt   = (unsigned short*)(ws + 48 * MB);
    float*          krdT = (float*)(ws + 56 * MB);           // 256KB
    (void)in_sizes; (void)n_in; (void)out_size; (void)ws_size;

    cast_f32_bf16<<<4096, 256, 0, stream>>>(states, Sb, 1024 * 1024);
    cast_f32_bf16<<<4096, 256, 0, stream>>>(key_states, Kb, 1024 * 1024);
    transpose_cast<<<256, 256, 0, stream>>>(Wq, Wqt, 1024, 1024);
    transpose_cast<<<256, 256, 0, stream>>>(Wk, Wqt + 1024 * 1024, 1024, 1024);
    transpose_cast<<<256, 256, 0, stream>>>(Wv, Wqt + 2 * 1024 * 1024, 1024, 1024);
    transpose_cast<<<256, 256, 0, stream>>>(Wo, Wot, 1024, 1024);

    gemm_qkv<<<768, 256, 0, stream>>>(Sb, Kb, Wqt, Qb, Kbf, Vb);

    kred_kernel<<<256, 256, 0, stream>>>(Kbf, krdT);
    transpose_v<<<1024, 256, 0, stream>>>(Vb, Vt);

    // bqkT overlays Sb/Kb — safe only after gemm_qkv consumed them (stream order).
    hipMemsetAsync(bqkT, 0, (size_t)4 * 1024 * 1024 * 4, stream);
    scatter_bias<<<64, 256, 0, stream>>>(ab, embs, scal, bqkT, 16384);
    pack_T<<<1024, 256, 0, stream>>>(masks, (unsigned*)bqkT);

    attn_kernel<<<1024, 256, 0, stream>>>(Qb, Kbf, Vt, (const unsigned*)bqkT, krdT, ctx);

    gemm_wo<<<256, 256, 0, stream>>>(ctx, Wot, (float*)d_out);
}